// Round 6
// baseline (571.874 us; speedup 1.0000x reference)
//
#include <hip/hip_runtime.h>

#define H96 96

// ---------------- degrees (int) ----------------
__global__ void deg_kernel(const int* __restrict__ src, const int* __restrict__ dst,
                           int* __restrict__ dout, int* __restrict__ din, int E) {
    int e = blockIdx.x * blockDim.x + threadIdx.x;
    if (e < E) {
        atomicAdd(dout + src[e], 1);
        atomicAdd(din + dst[e], 1);
    }
}

__global__ void norm_kernel(const int* __restrict__ dO, const int* __restrict__ dI,
                            float* __restrict__ no, float* __restrict__ ni, int N) {
    int i = blockIdx.x * blockDim.x + threadIdx.x;
    if (i < N) {
        no[i] = rsqrtf(fmaxf((float)dO[i], 1.0f));
        ni[i] = rsqrtf(fmaxf((float)dI[i], 1.0f));
    }
}

// ---------------- generic exclusive scan (3 kernels, n <= 256*256) ----------------
__global__ void scanA_kernel(const int* __restrict__ in, int* __restrict__ pre,
                             int* __restrict__ bsums, int n) {
    __shared__ int s[256];
    int i = blockIdx.x * 256 + threadIdx.x;
    int v = (i < n) ? in[i] : 0;
    s[threadIdx.x] = v;
    __syncthreads();
    for (int off = 1; off < 256; off <<= 1) {
        int t = (threadIdx.x >= off) ? s[threadIdx.x - off] : 0;
        __syncthreads();
        s[threadIdx.x] += t;
        __syncthreads();
    }
    if (i < n) pre[i] = s[threadIdx.x] - v;
    if (threadIdx.x == 255) bsums[blockIdx.x] = s[255];
}

__global__ void scanB_kernel(int* __restrict__ bsums, int nb) {
    __shared__ int s[256];
    int v = (threadIdx.x < nb) ? bsums[threadIdx.x] : 0;
    s[threadIdx.x] = v;
    __syncthreads();
    for (int off = 1; off < 256; off <<= 1) {
        int t = (threadIdx.x >= off) ? s[threadIdx.x - off] : 0;
        __syncthreads();
        s[threadIdx.x] += t;
        __syncthreads();
    }
    if (threadIdx.x < nb) bsums[threadIdx.x] = s[threadIdx.x] - v;
}

__global__ void scanC_kernel(const int* __restrict__ pre, const int* __restrict__ bsums,
                             int* __restrict__ out, int n) {
    int i = blockIdx.x * 256 + threadIdx.x;
    if (i < n) out[i] = pre[i] + bsums[blockIdx.x];
}

__global__ void rowfin_kernel(const int* __restrict__ pre, const int* __restrict__ bsums,
                              int* __restrict__ row_start, int* __restrict__ cursor,
                              int N, int E) {
    int i = blockIdx.x * 256 + threadIdx.x;
    if (i < N) {
        int v = pre[i] + bsums[blockIdx.x];
        row_start[i] = v;
        cursor[i] = v;
    }
    if (i == 0) row_start[N] = E;
}

__global__ void scatter_kernel(const int* __restrict__ src, const int* __restrict__ dst,
                               const int* __restrict__ perm, const float* __restrict__ norm_out,
                               int* __restrict__ cursor, int* __restrict__ csr_src,
                               int* __restrict__ csr_perm, float* __restrict__ csr_norm, int E) {
    int e = blockIdx.x * 256 + threadIdx.x;
    if (e < E) {
        int d = dst[e];
        int s = src[e];
        int p = atomicAdd(cursor + d, 1);
        csr_src[p] = s;
        csr_perm[p] = perm[s];
        csr_norm[p] = norm_out[s];
    }
}

// ---------------- low-contention counting sort by deg_in ----------------
__global__ void histblk_kernel(const int* __restrict__ deg, int* __restrict__ hb,
                               int N, int nb) {
    __shared__ int h[256];
    h[threadIdx.x] = 0;
    __syncthreads();
    int i = blockIdx.x * 256 + threadIdx.x;
    if (i < N) atomicAdd(&h[min(deg[i], 255)], 1);
    __syncthreads();
    hb[threadIdx.x * nb + blockIdx.x] = h[threadIdx.x];
}

__global__ void place_kernel(const int* __restrict__ deg, const int* __restrict__ hbs,
                             int* __restrict__ order, int N, int nb) {
    __shared__ int cur[256];
    cur[threadIdx.x] = hbs[threadIdx.x * nb + blockIdx.x];
    __syncthreads();
    int i = blockIdx.x * 256 + threadIdx.x;
    if (i < N) {
        int b = min(deg[i], 255);
        int p = atomicAdd(&cur[b], 1);
        order[p] = i;
    }
}

// wsum[c] = row sums of Wm, bsum = sum(bm)
__global__ void wsum_kernel(const float* __restrict__ Wm, const float* __restrict__ bm,
                            float* __restrict__ wsum, float* __restrict__ bsum) {
    int c = threadIdx.x;
    if (c < H96) {
        float s = 0.f;
        for (int j = 0; j < H96; j++) s += Wm[c * H96 + j];
        wsum[c] = s;
    }
    if (c == 0) {
        float s = 0.f;
        for (int j = 0; j < H96; j++) s += bm[j];
        bsum[0] = s;
    }
}

// ---------------- fp32 GEMM with in-dispatch split-K ----------------
// C[M,96] = A[M,K] @ B[K,96]. blockIdx.y==0: k in [0,ksplit) -> C0;
// blockIdx.y==1: k in [ksplit,K) -> C1. Launch gridDim.y=1 with ksplit=K for no split.
#define BM 128
#define BK 32
#define BKP 33
__global__ __launch_bounds__(256) void gemm_kernel(const float* __restrict__ A,
                                                   const float* __restrict__ B,
                                                   float* __restrict__ C0,
                                                   float* __restrict__ C1,
                                                   int M, int K, int ksplit) {
    __shared__ float As[BM * BKP];   // 128 x 33 = 16.9 KB
    __shared__ float Bs[BK * H96];   // 32 x 96  = 12 KB
    int kbeg = blockIdx.y ? ksplit : 0;
    int kend = blockIdx.y ? K : ksplit;
    float* __restrict__ C = blockIdx.y ? C1 : C0;
    int tid = threadIdx.x;
    int tx = tid & 7, ty = tid >> 3;     // 8 col groups x 32 row groups
    int row0 = blockIdx.x * BM;
    int r0 = ty * 4, c0 = tx * 12;
    alignas(16) float acc[4][12] = {};
    float4 pa[4], pb[3];
    int nk = (kend - kbeg + BK - 1) / BK;

    // stage tile 0 (A: 128x32 = 1024 float4, 4/thread; B: 768 float4, 3/thread)
#pragma unroll
    for (int i = 0; i < 4; i++) {
        int idx = tid + i * 256;
        int r = idx >> 3, kq = idx & 7;
        int gr = row0 + r, gk = kbeg + kq * 4;
        pa[i] = (gr < M && gk < kend) ? *(const float4*)(A + (size_t)gr * K + gk)
                                      : make_float4(0.f, 0.f, 0.f, 0.f);
    }
#pragma unroll
    for (int i = 0; i < 3; i++) {
        int idx = tid + i * 256;
        int kk = idx / 24, cq = idx - kk * 24;
        int gk = kbeg + kk;
        pb[i] = (gk < kend) ? *(const float4*)(B + (size_t)gk * H96 + cq * 4)
                            : make_float4(0.f, 0.f, 0.f, 0.f);
    }

    for (int t = 0; t < nk; t++) {
#pragma unroll
        for (int i = 0; i < 4; i++) {
            int idx = tid + i * 256;
            int r = idx >> 3, kq = idx & 7;
            As[r * BKP + kq * 4 + 0] = pa[i].x;
            As[r * BKP + kq * 4 + 1] = pa[i].y;
            As[r * BKP + kq * 4 + 2] = pa[i].z;
            As[r * BKP + kq * 4 + 3] = pa[i].w;
        }
#pragma unroll
        for (int i = 0; i < 3; i++) {
            int idx = tid + i * 256;
            int kk = idx / 24, cq = idx - kk * 24;
            *(float4*)(&Bs[kk * H96 + cq * 4]) = pb[i];
        }
        __syncthreads();

        if (t + 1 < nk) {
            int k0 = kbeg + (t + 1) * BK;
#pragma unroll
            for (int i = 0; i < 4; i++) {
                int idx = tid + i * 256;
                int r = idx >> 3, kq = idx & 7;
                int gr = row0 + r, gk = k0 + kq * 4;
                pa[i] = (gr < M && gk < kend) ? *(const float4*)(A + (size_t)gr * K + gk)
                                              : make_float4(0.f, 0.f, 0.f, 0.f);
            }
#pragma unroll
            for (int i = 0; i < 3; i++) {
                int idx = tid + i * 256;
                int kk = idx / 24, cq = idx - kk * 24;
                int gk = k0 + kk;
                pb[i] = (gk < kend) ? *(const float4*)(B + (size_t)gk * H96 + cq * 4)
                                    : make_float4(0.f, 0.f, 0.f, 0.f);
            }
        }

#pragma unroll 8
        for (int k = 0; k < BK; k++) {
            float a[4];
            alignas(16) float b[12];
#pragma unroll
            for (int i = 0; i < 4; i++) a[i] = As[(r0 + i) * BKP + k];
#pragma unroll
            for (int j = 0; j < 3; j++)
                *(float4*)&b[j * 4] = *(const float4*)&Bs[k * H96 + c0 + j * 4];
#pragma unroll
            for (int i = 0; i < 4; i++)
#pragma unroll
                for (int j = 0; j < 12; j++)
                    acc[i][j] = fmaf(a[i], b[j], acc[i][j]);
        }
        __syncthreads();
    }

#pragma unroll
    for (int i = 0; i < 4; i++) {
        int gr = row0 + r0 + i;
        if (gr < M) {
#pragma unroll
            for (int j = 0; j < 3; j++)
                *(float4*)(C + (size_t)gr * H96 + c0 + j * 4) = *(const float4*)&acc[i][j * 4];
        }
    }
}

// y += p  (float4 grid-stride)
__global__ void add_kernel(float4* __restrict__ y, const float4* __restrict__ p, int n4) {
    int i = blockIdx.x * blockDim.x + threadIdx.x;
    if (i < n4) {
        float4 a = y[i], b = p[i];
        a.x += b.x; a.y += b.y; a.z += b.z; a.w += b.w;
        y[i] = a;
    }
}

// ---------------- helpers ----------------
__device__ __forceinline__ void fma4(float4& a, float s, const float4& v) {
    a.x = fmaf(s, v.x, a.x);
    a.y = fmaf(s, v.y, a.y);
    a.z = fmaf(s, v.z, a.z);
    a.w = fmaf(s, v.w, a.w);
}

__device__ __forceinline__ float4 prelu4(float4 acc, float ni, float4 b, float4 a) {
    float4 h;
    h.x = fmaf(acc.x, ni, b.x); h.x = (h.x >= 0.f) ? h.x : a.x * h.x;
    h.y = fmaf(acc.y, ni, b.y); h.y = (h.y >= 0.f) ? h.y : a.y * h.y;
    h.z = fmaf(acc.z, ni, b.z); h.z = (h.z >= 0.f) ? h.z : a.z * h.z;
    h.w = fmaf(acc.w, ni, b.w); h.w = (h.w >= 0.f) ? h.w : a.w * h.w;
    return h;
}

// ---------------- layer-1 dual-view SpMM, float4, 4-edge unroll ----------------
__global__ __launch_bounds__(384) void spmm1_dual(
        const float4* __restrict__ y4, const int* __restrict__ row_start,
        const int* __restrict__ csr_src, const int* __restrict__ csr_perm,
        const float* __restrict__ csr_norm, const int* __restrict__ order,
        const float* __restrict__ norm_out, const float* __restrict__ norm_in,
        const float* __restrict__ b1, const float* __restrict__ a1,
        float4* __restrict__ h1, float4* __restrict__ h2, int N) {
    int g = blockIdx.x * 16 + threadIdx.y;
    if (g >= N) return;
    int d = order[g];
    int tx = threadIdx.x;
    int beg = row_start[d], end = row_start[d + 1];
    const float4* yt = y4 + tx;
    float4 acc1 = make_float4(0.f, 0.f, 0.f, 0.f);
    float4 acc2 = make_float4(0.f, 0.f, 0.f, 0.f);
    int j = beg;
    for (; j + 4 <= end; j += 4) {
        int s0 = csr_src[j], s1 = csr_src[j + 1], s2 = csr_src[j + 2], s3 = csr_src[j + 3];
        int p0 = csr_perm[j], p1 = csr_perm[j + 1], p2 = csr_perm[j + 2], p3 = csr_perm[j + 3];
        float n0 = csr_norm[j], n1 = csr_norm[j + 1], n2 = csr_norm[j + 2], n3 = csr_norm[j + 3];
        float4 u0 = yt[(size_t)s0 * 24], u1 = yt[(size_t)s1 * 24];
        float4 u2 = yt[(size_t)s2 * 24], u3 = yt[(size_t)s3 * 24];
        float4 w0 = yt[(size_t)p0 * 24], w1 = yt[(size_t)p1 * 24];
        float4 w2 = yt[(size_t)p2 * 24], w3 = yt[(size_t)p3 * 24];
        fma4(acc1, n0, u0); fma4(acc1, n1, u1); fma4(acc1, n2, u2); fma4(acc1, n3, u3);
        fma4(acc2, n0, w0); fma4(acc2, n1, w1); fma4(acc2, n2, w2); fma4(acc2, n3, w3);
    }
    for (; j < end; j++) {
        int s = csr_src[j];
        int p = csr_perm[j];
        float n = csr_norm[j];
        fma4(acc1, n, yt[(size_t)s * 24]);
        fma4(acc2, n, yt[(size_t)p * 24]);
    }
    float ni = norm_in[d], no = norm_out[d];
    float4 bb = ((const float4*)b1)[tx];
    float4 aa = ((const float4*)a1)[tx];
    float4 r1 = prelu4(acc1, ni, bb, aa);
    float4 r2 = prelu4(acc2, ni, bb, aa);
    r1.x *= no; r1.y *= no; r1.z *= no; r1.w *= no;
    r2.x *= no; r2.y *= no; r2.z *= no; r2.w *= no;
    h1[(size_t)d * 24 + tx] = r1;
    h2[(size_t)d * 24 + tx] = r2;
}

// ---------------- layer-2 dual-view SpMM + fused final dot ----------------
__global__ __launch_bounds__(384) void spmm2_dual(
        const float4* __restrict__ t4,
        const int* __restrict__ row_start, const int* __restrict__ csr_src,
        const int* __restrict__ order, const float* __restrict__ norm_in,
        const float* __restrict__ b2, const float* __restrict__ a2,
        const float* __restrict__ wsum, const float* __restrict__ bsum,
        float* __restrict__ outp, int N) {
    int g = blockIdx.x * 16 + threadIdx.y;
    int tx = threadIdx.x;
    int ty = threadIdx.y;
    bool valid = (g < N);
    int d = valid ? order[g] : 0;
    int beg = 0, end = 0;
    if (valid) { beg = row_start[d]; end = row_start[d + 1]; }
    const float4* t1 = t4 + tx;
    const float4* t2 = t4 + (size_t)N * 24 + tx;
    float4 acc1 = make_float4(0.f, 0.f, 0.f, 0.f);
    float4 acc2 = make_float4(0.f, 0.f, 0.f, 0.f);
    int j = beg;
    for (; j + 4 <= end; j += 4) {
        int s0 = csr_src[j], s1 = csr_src[j + 1], s2 = csr_src[j + 2], s3 = csr_src[j + 3];
        float4 u0 = t1[(size_t)s0 * 24], u1 = t1[(size_t)s1 * 24];
        float4 u2 = t1[(size_t)s2 * 24], u3 = t1[(size_t)s3 * 24];
        float4 w0 = t2[(size_t)s0 * 24], w1 = t2[(size_t)s1 * 24];
        float4 w2 = t2[(size_t)s2 * 24], w3 = t2[(size_t)s3 * 24];
        fma4(acc1, 1.f, u0); fma4(acc1, 1.f, u1); fma4(acc1, 1.f, u2); fma4(acc1, 1.f, u3);
        fma4(acc2, 1.f, w0); fma4(acc2, 1.f, w1); fma4(acc2, 1.f, w2); fma4(acc2, 1.f, w3);
    }
    for (; j < end; j++) {
        int s = csr_src[j];
        fma4(acc1, 1.f, t1[(size_t)s * 24]);
        fma4(acc2, 1.f, t2[(size_t)s * 24]);
    }
    float ni = valid ? norm_in[d] : 0.f;
    float4 bb = ((const float4*)b2)[tx];
    float4 aa = ((const float4*)a2)[tx];
    float4 wv = ((const float4*)wsum)[tx];
    float4 r1 = prelu4(acc1, ni, bb, aa);
    float4 r2 = prelu4(acc2, ni, bb, aa);
    float p1 = r1.x * wv.x + r1.y * wv.y + r1.z * wv.z + r1.w * wv.w;
    float p2 = r2.x * wv.x + r2.y * wv.y + r2.z * wv.z + r2.w * wv.w;
    __shared__ float red1[16][24];
    __shared__ float red2[16][24];
    red1[ty][tx] = p1;
    red2[ty][tx] = p2;
    __syncthreads();
    if (tx == 0 && valid) {
        float s1 = 0.f, s2 = 0.f;
#pragma unroll
        for (int k = 0; k < 24; k++) { s1 += red1[ty][k]; s2 += red2[ty][k]; }
        outp[d] = s1 + bsum[0];
        outp[N + d] = s2 + bsum[0];
    }
}

extern "C" void kernel_launch(void* const* d_in, const int* in_sizes, int n_in,
                              void* d_out, int out_size, void* d_ws, size_t ws_size,
                              hipStream_t stream) {
    const float* x    = (const float*)d_in[0];
    const int*   src  = (const int*)d_in[1];
    const int*   dst  = (const int*)d_in[2];
    const int*   perm = (const int*)d_in[3];
    const float* W1   = (const float*)d_in[4];
    const float* b1   = (const float*)d_in[5];
    const float* a1   = (const float*)d_in[6];
    const float* W2   = (const float*)d_in[7];
    const float* b2   = (const float*)d_in[8];
    const float* a2   = (const float*)d_in[9];
    const float* Wm   = (const float*)d_in[10];
    const float* bm   = (const float*)d_in[11];
    float* out = (float*)d_out;

    int E = in_sizes[1];
    int N = in_sizes[3];
    int F = in_sizes[0] / N;

    size_t NP = ((size_t)N + 256) & ~(size_t)255;
    size_t EP = ((size_t)E + 255) & ~(size_t)255;
    int nb = (N + 255) / 256;
    size_t HB = ((size_t)256 * nb + 255) & ~(size_t)255;

    int* deg_out   = (int*)d_ws;          // NP
    int* deg_in    = deg_out + NP;        // NP
    int* pre       = deg_in + NP;         // NP
    int* row_start = pre + NP;            // NP
    int* cursor    = row_start + NP;      // NP
    int* order     = cursor + NP;         // NP
    int* bsums     = order + NP;          // 256
    int* hb        = bsums + 256;         // HB
    int* hbs       = hb + HB;             // HB
    int* hpre      = hbs + HB;            // HB
    int* csr_src   = hpre + HB;           // EP
    int* csr_perm  = csr_src + EP;        // EP
    float* csr_norm = (float*)(csr_perm + EP); // EP
    float* norm_out = csr_norm + EP;           // NP
    float* norm_in  = norm_out + NP;           // NP
    float* wsum     = norm_in + NP;            // 128
    float* bsum     = wsum + 128;              // 128
    float* tbuf     = bsum + 128;              // 2N*96 (first N*96 doubles as y)
    float* h1s      = tbuf + (size_t)2 * N * H96;  // 2N*96
    float* yp1      = h1s + (size_t)2 * N * H96;   // N*96 (split-K partial)

    hipMemsetAsync(deg_out, 0, 2 * NP * sizeof(int), stream);
    deg_kernel<<<(E + 255) / 256, 256, 0, stream>>>(src, dst, deg_out, deg_in, E);
    norm_kernel<<<(N + 255) / 256, 256, 0, stream>>>(deg_out, deg_in, norm_out, norm_in, N);

    scanA_kernel<<<nb, 256, 0, stream>>>(deg_in, pre, bsums, N);
    scanB_kernel<<<1, 256, 0, stream>>>(bsums, nb);
    rowfin_kernel<<<nb, 256, 0, stream>>>(pre, bsums, row_start, cursor, N, E);
    scatter_kernel<<<(E + 255) / 256, 256, 0, stream>>>(src, dst, perm, norm_out, cursor,
                                                        csr_src, csr_perm, csr_norm, E);

    histblk_kernel<<<nb, 256, 0, stream>>>(deg_in, hb, N, nb);
    int n2 = 256 * nb;
    int nb2 = (n2 + 255) / 256;
    scanA_kernel<<<nb2, 256, 0, stream>>>(hb, hpre, bsums, n2);
    scanB_kernel<<<1, 256, 0, stream>>>(bsums, nb2);
    scanC_kernel<<<nb2, 256, 0, stream>>>(hpre, bsums, hbs, n2);
    place_kernel<<<nb, 256, 0, stream>>>(deg_in, hbs, order, N, nb);

    wsum_kernel<<<1, 128, 0, stream>>>(Wm, bm, wsum, bsum);

    float* y = tbuf;  // reuse: y dead before tbuf is written
    // y = x @ W1, split-K in one dispatch: part0 -> y, part1 -> yp1; then y += yp1
    int nblk1 = (N + BM - 1) / BM;
    int ksplit = ((F / BK) / 2) * BK;  // 500 -> 256... (15 tiles: 8/7 split)
    if (ksplit <= 0 || ksplit >= F) ksplit = F / 2;
    gemm_kernel<<<dim3(nblk1, 2), 256, 0, stream>>>(x, W1, y, yp1, N, F, ksplit);
    int n4 = N * H96 / 4;
    add_kernel<<<(n4 + 255) / 256, 256, 0, stream>>>((float4*)y, (const float4*)yp1, n4);

    int nsb = (N + 15) / 16;
    spmm1_dual<<<nsb, dim3(24, 16), 0, stream>>>(
        (const float4*)y, row_start, csr_src, csr_perm, csr_norm, order, norm_out, norm_in,
        b1, a1, (float4*)h1s, (float4*)(h1s + (size_t)N * H96), N);

    // tbuf[2N,96] = h1s @ W2 — M=100000 -> 782 blocks, no split
    int nblk2 = (2 * N + BM - 1) / BM;
    gemm_kernel<<<dim3(nblk2, 1), 256, 0, stream>>>(h1s, W2, tbuf, nullptr, 2 * N, H96, H96);

    spmm2_dual<<<nsb, dim3(24, 16), 0, stream>>>(
        (const float4*)tbuf, row_start, csr_src, order, norm_in, b2, a2,
        wsum, bsum, out, N);
}

// Round 7
// 566.574 us; speedup vs baseline: 1.0094x; 1.0094x over previous
//
#include <hip/hip_runtime.h>

#define H96 96

// ---------------- degrees (int) ----------------
__global__ void deg_kernel(const int* __restrict__ src, const int* __restrict__ dst,
                           int* __restrict__ dout, int* __restrict__ din, int E) {
    int e = blockIdx.x * blockDim.x + threadIdx.x;
    if (e < E) {
        atomicAdd(dout + src[e], 1);
        atomicAdd(din + dst[e], 1);
    }
}

__global__ void norm_kernel(const int* __restrict__ dO, const int* __restrict__ dI,
                            float* __restrict__ no, float* __restrict__ ni, int N) {
    int i = blockIdx.x * blockDim.x + threadIdx.x;
    if (i < N) {
        no[i] = rsqrtf(fmaxf((float)dO[i], 1.0f));
        ni[i] = rsqrtf(fmaxf((float)dI[i], 1.0f));
    }
}

// ---------------- generic exclusive scan (3 kernels, n <= 256*256) ----------------
__global__ void scanA_kernel(const int* __restrict__ in, int* __restrict__ pre,
                             int* __restrict__ bsums, int n) {
    __shared__ int s[256];
    int i = blockIdx.x * 256 + threadIdx.x;
    int v = (i < n) ? in[i] : 0;
    s[threadIdx.x] = v;
    __syncthreads();
    for (int off = 1; off < 256; off <<= 1) {
        int t = (threadIdx.x >= off) ? s[threadIdx.x - off] : 0;
        __syncthreads();
        s[threadIdx.x] += t;
        __syncthreads();
    }
    if (i < n) pre[i] = s[threadIdx.x] - v;
    if (threadIdx.x == 255) bsums[blockIdx.x] = s[255];
}

__global__ void scanB_kernel(int* __restrict__ bsums, int nb) {
    __shared__ int s[256];
    int v = (threadIdx.x < nb) ? bsums[threadIdx.x] : 0;
    s[threadIdx.x] = v;
    __syncthreads();
    for (int off = 1; off < 256; off <<= 1) {
        int t = (threadIdx.x >= off) ? s[threadIdx.x - off] : 0;
        __syncthreads();
        s[threadIdx.x] += t;
        __syncthreads();
    }
    if (threadIdx.x < nb) bsums[threadIdx.x] = s[threadIdx.x] - v;
}

__global__ void scanC_kernel(const int* __restrict__ pre, const int* __restrict__ bsums,
                             int* __restrict__ out, int n) {
    int i = blockIdx.x * 256 + threadIdx.x;
    if (i < n) out[i] = pre[i] + bsums[blockIdx.x];
}

__global__ void rowfin_kernel(const int* __restrict__ pre, const int* __restrict__ bsums,
                              int* __restrict__ row_start, int* __restrict__ cursor,
                              int N, int E) {
    int i = blockIdx.x * 256 + threadIdx.x;
    if (i < N) {
        int v = pre[i] + bsums[blockIdx.x];
        row_start[i] = v;
        cursor[i] = v;
    }
    if (i == 0) row_start[N] = E;
}

__global__ void scatter_kernel(const int* __restrict__ src, const int* __restrict__ dst,
                               const int* __restrict__ perm, const float* __restrict__ norm_out,
                               int* __restrict__ cursor, int* __restrict__ csr_src,
                               int* __restrict__ csr_perm, float* __restrict__ csr_norm, int E) {
    int e = blockIdx.x * 256 + threadIdx.x;
    if (e < E) {
        int d = dst[e];
        int s = src[e];
        int p = atomicAdd(cursor + d, 1);
        csr_src[p] = s;
        csr_perm[p] = perm[s];
        csr_norm[p] = norm_out[s];
    }
}

// ---------------- low-contention counting sort by deg_in ----------------
__global__ void histblk_kernel(const int* __restrict__ deg, int* __restrict__ hb,
                               int N, int nb) {
    __shared__ int h[256];
    h[threadIdx.x] = 0;
    __syncthreads();
    int i = blockIdx.x * 256 + threadIdx.x;
    if (i < N) atomicAdd(&h[min(deg[i], 255)], 1);
    __syncthreads();
    hb[threadIdx.x * nb + blockIdx.x] = h[threadIdx.x];
}

__global__ void place_kernel(const int* __restrict__ deg, const int* __restrict__ hbs,
                             int* __restrict__ order, int N, int nb) {
    __shared__ int cur[256];
    cur[threadIdx.x] = hbs[threadIdx.x * nb + blockIdx.x];
    __syncthreads();
    int i = blockIdx.x * 256 + threadIdx.x;
    if (i < N) {
        int b = min(deg[i], 255);
        int p = atomicAdd(&cur[b], 1);
        order[p] = i;
    }
}

// wsum[c] = row sums of Wm, bsum = sum(bm)
__global__ void wsum_kernel(const float* __restrict__ Wm, const float* __restrict__ bm,
                            float* __restrict__ wsum, float* __restrict__ bsum) {
    int c = threadIdx.x;
    if (c < H96) {
        float s = 0.f;
        for (int j = 0; j < H96; j++) s += Wm[c * H96 + j];
        wsum[c] = s;
    }
    if (c == 0) {
        float s = 0.f;
        for (int j = 0; j < H96; j++) s += bm[j];
        bsum[0] = s;
    }
}

// ---------------- fp32 GEMM: C[M,96] = A[M,K] @ B[K,96] ----------------
// 8x12 thread tile; A-tile stored col-major in LDS so A-frag = 2x ds_read_b128.
#define BM 128
#define BK 32
#define ASTR 132   // col-major A row stride (floats): keeps 16B align (132%4==0), spreads banks
__global__ __launch_bounds__(256) void gemm_kernel(const float* __restrict__ A,
                                                   const float* __restrict__ B,
                                                   float* __restrict__ C, int M, int K) {
    __shared__ float As[BK * ASTR];  // [k][r], 32 x 132 = 16.9 KB
    __shared__ float Bs[BK * H96];   // [k][c], 32 x 96  = 12 KB
    int tid = threadIdx.x;
    int tx = tid & 7, ty = tid >> 3;     // 8 col-groups(12) x 16 row-groups(8); ty in [0,32) but use tid>>4
    // remap: 16 row groups x 8 col groups x ... need 256 threads -> (tx in [0,8), ry in [0,16), but 8*16=128)
    // use: tx = tid & 7 (col group of 12), ry = (tid >> 3) & 15 is 16 groups only for 128 threads.
    // Correct mapping for 256 threads: col group cg in [0,8), row group rg in [0,16), plus kslice? No:
    // 128 rows/8 = 16 row groups, 96 cols/12 = 8 col groups -> 128 thread-tiles. We have 256 threads,
    // so split k: each thread handles all k (standard). Use 16x16 grid: rg = tid>>4 (16), cg8 = tid&15?
    // Simplest consistent mapping: rg in [0,16): r0 = rg*8 ; cg in [0,16): two threads share a col group?
    // -> Use 256 threads as 16 rg x 16 half-col-groups of 6: c0 = cg*6, 8 rows x 6 cols = 48 FMA. NO.
    // Final choice: 256 threads = 32 rg x 8 cg, r0 = rg*4? That's the old tile.
    // => use 128x96 tile with 256 threads: rg = tid>>4 in [0,16), cg = tid&15 in [0,16)? 96/16=6.
    // Tile: 8 rows x 6 cols = 48 FMA but with b128 A reads (2) and 12-float... 6 floats != float4.
    // Keep it clean: 8 rows x 12 cols, 128 thread-tiles, 256 threads -> TWO tiles of 64 rows each.
    int rg = tid >> 3;                   // [0,32): row group of 4? No -- see below.
    (void)rg; (void)ty;
    // FINAL mapping (verified): treat block as 256 threads covering 128x96 with 8x12 per-thread tiles
    // arranged as 16 row-groups x 8 col-groups = 128 tiles... 256 threads means 2 threads per tile is wrong.
    // Instead: BM=256 rows? No. Use 8x6 tiles: 16 rg x 16 cg = 256 threads, r0=rg*8, c0=cg*6.
    int rg16 = tid >> 4;                 // [0,16) row group of 8 rows
    int cg16 = tid & 15;                 // [0,16) col group of 6 cols
    int row0 = blockIdx.x * BM;
    int r0 = rg16 * 8, c0 = cg16 * 6;
    float acc[8][6] = {};
    float4 pa[4], pb[3];
    int nk = (K + BK - 1) / BK;

    // stage tile 0 (A: 128x32 = 1024 float4-loads worth, 4/thread; B: 768 float4, 3/thread)
#pragma unroll
    for (int i = 0; i < 4; i++) {
        int idx = tid + i * 256;
        int r = idx >> 3, kq = idx & 7;
        int gr = row0 + r, gk = kq * 4;
        pa[i] = (gr < M && gk < K) ? *(const float4*)(A + (size_t)gr * K + gk)
                                   : make_float4(0.f, 0.f, 0.f, 0.f);
    }
#pragma unroll
    for (int i = 0; i < 3; i++) {
        int idx = tid + i * 256;
        int kk = idx / 24, cq = idx - kk * 24;
        pb[i] = (kk < K) ? *(const float4*)(B + (size_t)kk * H96 + cq * 4)
                         : make_float4(0.f, 0.f, 0.f, 0.f);
    }

    for (int t = 0; t < nk; t++) {
        // write staged regs: A col-major As[k][r]
#pragma unroll
        for (int i = 0; i < 4; i++) {
            int idx = tid + i * 256;
            int r = idx >> 3, kq = idx & 7;
            As[(kq * 4 + 0) * ASTR + r] = pa[i].x;
            As[(kq * 4 + 1) * ASTR + r] = pa[i].y;
            As[(kq * 4 + 2) * ASTR + r] = pa[i].z;
            As[(kq * 4 + 3) * ASTR + r] = pa[i].w;
        }
#pragma unroll
        for (int i = 0; i < 3; i++) {
            int idx = tid + i * 256;
            int kk = idx / 24, cq = idx - kk * 24;
            *(float4*)(&Bs[kk * H96 + cq * 4]) = pb[i];
        }
        __syncthreads();

        if (t + 1 < nk) {
            int k0 = (t + 1) * BK;
#pragma unroll
            for (int i = 0; i < 4; i++) {
                int idx = tid + i * 256;
                int r = idx >> 3, kq = idx & 7;
                int gr = row0 + r, gk = k0 + kq * 4;
                pa[i] = (gr < M && gk < K) ? *(const float4*)(A + (size_t)gr * K + gk)
                                           : make_float4(0.f, 0.f, 0.f, 0.f);
            }
#pragma unroll
            for (int i = 0; i < 3; i++) {
                int idx = tid + i * 256;
                int kk = idx / 24, cq = idx - kk * 24;
                int gk = k0 + kk;
                pb[i] = (gk < K) ? *(const float4*)(B + (size_t)gk * H96 + cq * 4)
                                 : make_float4(0.f, 0.f, 0.f, 0.f);
            }
        }

#pragma unroll 4
        for (int k = 0; k < BK; k++) {
            // A fragment: 8 consecutive rows -> 2x ds_read_b128
            float4 a0 = *(const float4*)&As[k * ASTR + r0];
            float4 a1 = *(const float4*)&As[k * ASTR + r0 + 4];
            // B fragment: 6 cols -> aligned float4 + float2 (c0 = cg*6, even cg -> 8-align; odd -> 2-align)
            float b[6];
#pragma unroll
            for (int j = 0; j < 6; j++) b[j] = Bs[k * H96 + c0 + j];
            float a[8] = {a0.x, a0.y, a0.z, a0.w, a1.x, a1.y, a1.z, a1.w};
#pragma unroll
            for (int i = 0; i < 8; i++)
#pragma unroll
                for (int j = 0; j < 6; j++)
                    acc[i][j] = fmaf(a[i], b[j], acc[i][j]);
        }
        __syncthreads();
    }

#pragma unroll
    for (int i = 0; i < 8; i++) {
        int gr = row0 + r0 + i;
        if (gr < M) {
            float* cp = C + (size_t)gr * H96 + c0;
#pragma unroll
            for (int j = 0; j < 6; j++) cp[j] = acc[i][j];
        }
    }
}

// ---------------- helpers ----------------
__device__ __forceinline__ void fma4(float4& a, float s, const float4& v) {
    a.x = fmaf(s, v.x, a.x);
    a.y = fmaf(s, v.y, a.y);
    a.z = fmaf(s, v.z, a.z);
    a.w = fmaf(s, v.w, a.w);
}

__device__ __forceinline__ float4 prelu4(float4 acc, float ni, float4 b, float4 a) {
    float4 h;
    h.x = fmaf(acc.x, ni, b.x); h.x = (h.x >= 0.f) ? h.x : a.x * h.x;
    h.y = fmaf(acc.y, ni, b.y); h.y = (h.y >= 0.f) ? h.y : a.y * h.y;
    h.z = fmaf(acc.z, ni, b.z); h.z = (h.z >= 0.f) ? h.z : a.z * h.z;
    h.w = fmaf(acc.w, ni, b.w); h.w = (h.w >= 0.f) ? h.w : a.w * h.w;
    return h;
}

// ---------------- layer-1 dual-view SpMM, float4, 8-edge unroll ----------------
__global__ __launch_bounds__(384) void spmm1_dual(
        const float4* __restrict__ y4, const int* __restrict__ row_start,
        const int* __restrict__ csr_src, const int* __restrict__ csr_perm,
        const float* __restrict__ csr_norm, const int* __restrict__ order,
        const float* __restrict__ norm_out, const float* __restrict__ norm_in,
        const float* __restrict__ b1, const float* __restrict__ a1,
        float4* __restrict__ h1, float4* __restrict__ h2, int N) {
    int g = blockIdx.x * 16 + threadIdx.y;
    if (g >= N) return;
    int d = order[g];
    int tx = threadIdx.x;
    int beg = row_start[d], end = row_start[d + 1];
    const float4* yt = y4 + tx;
    float4 acc1 = make_float4(0.f, 0.f, 0.f, 0.f);
    float4 acc2 = make_float4(0.f, 0.f, 0.f, 0.f);
    int j = beg;
    for (; j + 8 <= end; j += 8) {
        int s[8], p[8];
        float n[8];
#pragma unroll
        for (int q = 0; q < 8; q++) {
            s[q] = csr_src[j + q];
            p[q] = csr_perm[j + q];
            n[q] = csr_norm[j + q];
        }
        float4 u[8], w[8];
#pragma unroll
        for (int q = 0; q < 8; q++) u[q] = yt[(size_t)s[q] * 24];
#pragma unroll
        for (int q = 0; q < 8; q++) w[q] = yt[(size_t)p[q] * 24];
#pragma unroll
        for (int q = 0; q < 8; q++) { fma4(acc1, n[q], u[q]); fma4(acc2, n[q], w[q]); }
    }
    for (; j < end; j++) {
        int s = csr_src[j];
        int p = csr_perm[j];
        float n = csr_norm[j];
        fma4(acc1, n, yt[(size_t)s * 24]);
        fma4(acc2, n, yt[(size_t)p * 24]);
    }
    float ni = norm_in[d], no = norm_out[d];
    float4 bb = ((const float4*)b1)[tx];
    float4 aa = ((const float4*)a1)[tx];
    float4 r1 = prelu4(acc1, ni, bb, aa);
    float4 r2 = prelu4(acc2, ni, bb, aa);
    r1.x *= no; r1.y *= no; r1.z *= no; r1.w *= no;
    r2.x *= no; r2.y *= no; r2.z *= no; r2.w *= no;
    h1[(size_t)d * 24 + tx] = r1;
    h2[(size_t)d * 24 + tx] = r2;
}

// ---------------- layer-2 dual-view SpMM + fused final dot, 8-edge unroll ----------------
__global__ __launch_bounds__(384) void spmm2_dual(
        const float4* __restrict__ t4,
        const int* __restrict__ row_start, const int* __restrict__ csr_src,
        const int* __restrict__ order, const float* __restrict__ norm_in,
        const float* __restrict__ b2, const float* __restrict__ a2,
        const float* __restrict__ wsum, const float* __restrict__ bsum,
        float* __restrict__ outp, int N) {
    int g = blockIdx.x * 16 + threadIdx.y;
    int tx = threadIdx.x;
    int ty = threadIdx.y;
    bool valid = (g < N);
    int d = valid ? order[g] : 0;
    int beg = 0, end = 0;
    if (valid) { beg = row_start[d]; end = row_start[d + 1]; }
    const float4* t1 = t4 + tx;
    const float4* t2 = t4 + (size_t)N * 24 + tx;
    float4 acc1 = make_float4(0.f, 0.f, 0.f, 0.f);
    float4 acc2 = make_float4(0.f, 0.f, 0.f, 0.f);
    int j = beg;
    for (; j + 8 <= end; j += 8) {
        int s[8];
#pragma unroll
        for (int q = 0; q < 8; q++) s[q] = csr_src[j + q];
        float4 u[8], w[8];
#pragma unroll
        for (int q = 0; q < 8; q++) u[q] = t1[(size_t)s[q] * 24];
#pragma unroll
        for (int q = 0; q < 8; q++) w[q] = t2[(size_t)s[q] * 24];
#pragma unroll
        for (int q = 0; q < 8; q++) { fma4(acc1, 1.f, u[q]); fma4(acc2, 1.f, w[q]); }
    }
    for (; j < end; j++) {
        int s = csr_src[j];
        fma4(acc1, 1.f, t1[(size_t)s * 24]);
        fma4(acc2, 1.f, t2[(size_t)s * 24]);
    }
    float ni = valid ? norm_in[d] : 0.f;
    float4 bb = ((const float4*)b2)[tx];
    float4 aa = ((const float4*)a2)[tx];
    float4 wv = ((const float4*)wsum)[tx];
    float4 r1 = prelu4(acc1, ni, bb, aa);
    float4 r2 = prelu4(acc2, ni, bb, aa);
    float p1 = r1.x * wv.x + r1.y * wv.y + r1.z * wv.z + r1.w * wv.w;
    float p2 = r2.x * wv.x + r2.y * wv.y + r2.z * wv.z + r2.w * wv.w;
    __shared__ float red1[16][24];
    __shared__ float red2[16][24];
    red1[ty][tx] = p1;
    red2[ty][tx] = p2;
    __syncthreads();
    if (tx == 0 && valid) {
        float s1 = 0.f, s2 = 0.f;
#pragma unroll
        for (int k = 0; k < 24; k++) { s1 += red1[ty][k]; s2 += red2[ty][k]; }
        outp[d] = s1 + bsum[0];
        outp[N + d] = s2 + bsum[0];
    }
}

extern "C" void kernel_launch(void* const* d_in, const int* in_sizes, int n_in,
                              void* d_out, int out_size, void* d_ws, size_t ws_size,
                              hipStream_t stream) {
    const float* x    = (const float*)d_in[0];
    const int*   src  = (const int*)d_in[1];
    const int*   dst  = (const int*)d_in[2];
    const int*   perm = (const int*)d_in[3];
    const float* W1   = (const float*)d_in[4];
    const float* b1   = (const float*)d_in[5];
    const float* a1   = (const float*)d_in[6];
    const float* W2   = (const float*)d_in[7];
    const float* b2   = (const float*)d_in[8];
    const float* a2   = (const float*)d_in[9];
    const float* Wm   = (const float*)d_in[10];
    const float* bm   = (const float*)d_in[11];
    float* out = (float*)d_out;

    int E = in_sizes[1];
    int N = in_sizes[3];
    int F = in_sizes[0] / N;

    size_t NP = ((size_t)N + 256) & ~(size_t)255;
    size_t EP = ((size_t)E + 255) & ~(size_t)255;
    int nb = (N + 255) / 256;
    size_t HB = ((size_t)256 * nb + 255) & ~(size_t)255;

    int* deg_out   = (int*)d_ws;          // NP
    int* deg_in    = deg_out + NP;        // NP
    int* pre       = deg_in + NP;         // NP
    int* row_start = pre + NP;            // NP
    int* cursor    = row_start + NP;      // NP
    int* order     = cursor + NP;         // NP
    int* bsums     = order + NP;          // 256
    int* hb        = bsums + 256;         // HB
    int* hbs       = hb + HB;             // HB
    int* hpre      = hbs + HB;            // HB
    int* csr_src   = hpre + HB;           // EP
    int* csr_perm  = csr_src + EP;        // EP
    float* csr_norm = (float*)(csr_perm + EP); // EP
    float* norm_out = csr_norm + EP;           // NP
    float* norm_in  = norm_out + NP;           // NP
    float* wsum     = norm_in + NP;            // 128
    float* bsum     = wsum + 128;              // 128
    float* tbuf     = bsum + 128;              // 2N*96 (first N*96 doubles as y)
    float* h1s      = tbuf + (size_t)2 * N * H96;  // 2N*96

    hipMemsetAsync(deg_out, 0, 2 * NP * sizeof(int), stream);
    deg_kernel<<<(E + 255) / 256, 256, 0, stream>>>(src, dst, deg_out, deg_in, E);
    norm_kernel<<<(N + 255) / 256, 256, 0, stream>>>(deg_out, deg_in, norm_out, norm_in, N);

    scanA_kernel<<<nb, 256, 0, stream>>>(deg_in, pre, bsums, N);
    scanB_kernel<<<1, 256, 0, stream>>>(bsums, nb);
    rowfin_kernel<<<nb, 256, 0, stream>>>(pre, bsums, row_start, cursor, N, E);
    scatter_kernel<<<(E + 255) / 256, 256, 0, stream>>>(src, dst, perm, norm_out, cursor,
                                                        csr_src, csr_perm, csr_norm, E);

    histblk_kernel<<<nb, 256, 0, stream>>>(deg_in, hb, N, nb);
    int n2 = 256 * nb;
    int nb2 = (n2 + 255) / 256;
    scanA_kernel<<<nb2, 256, 0, stream>>>(hb, hpre, bsums, n2);
    scanB_kernel<<<1, 256, 0, stream>>>(bsums, nb2);
    scanC_kernel<<<nb2, 256, 0, stream>>>(hpre, bsums, hbs, n2);
    place_kernel<<<nb, 256, 0, stream>>>(deg_in, hbs, order, N, nb);

    wsum_kernel<<<1, 128, 0, stream>>>(Wm, bm, wsum, bsum);

    float* y = tbuf;  // reuse: y dead before tbuf is written
    gemm_kernel<<<(N + BM - 1) / BM, 256, 0, stream>>>(x, W1, y, N, F);

    int nsb = (N + 15) / 16;
    spmm1_dual<<<nsb, dim3(24, 16), 0, stream>>>(
        (const float4*)y, row_start, csr_src, csr_perm, csr_norm, order, norm_out, norm_in,
        b1, a1, (float4*)h1s, (float4*)(h1s + (size_t)N * H96), N);

    gemm_kernel<<<(2 * N + BM - 1) / BM, 256, 0, stream>>>(h1s, W2, tbuf, 2 * N, H96);

    spmm2_dual<<<nsb, dim3(24, 16), 0, stream>>>(
        (const float4*)tbuf, row_start, csr_src, order, norm_in, b2, a2,
        wsum, bsum, out, N);
}

// Round 8
// 543.152 us; speedup vs baseline: 1.0529x; 1.0431x over previous
//
#include <hip/hip_runtime.h>

#define H96 96

typedef __attribute__((ext_vector_type(8))) short bf16x8_t;
typedef __attribute__((ext_vector_type(4))) float f32x4_t;

// ---------------- degrees (int) ----------------
__global__ void deg_kernel(const int* __restrict__ src, const int* __restrict__ dst,
                           int* __restrict__ dout, int* __restrict__ din, int E) {
    int e = blockIdx.x * blockDim.x + threadIdx.x;
    if (e < E) {
        atomicAdd(dout + src[e], 1);
        atomicAdd(din + dst[e], 1);
    }
}

__global__ void norm_kernel(const int* __restrict__ dO, const int* __restrict__ dI,
                            float* __restrict__ no, float* __restrict__ ni, int N) {
    int i = blockIdx.x * blockDim.x + threadIdx.x;
    if (i < N) {
        no[i] = rsqrtf(fmaxf((float)dO[i], 1.0f));
        ni[i] = rsqrtf(fmaxf((float)dI[i], 1.0f));
    }
}

// ---------------- generic exclusive scan (3 kernels, n <= 256*256) ----------------
__global__ void scanA_kernel(const int* __restrict__ in, int* __restrict__ pre,
                             int* __restrict__ bsums, int n) {
    __shared__ int s[256];
    int i = blockIdx.x * 256 + threadIdx.x;
    int v = (i < n) ? in[i] : 0;
    s[threadIdx.x] = v;
    __syncthreads();
    for (int off = 1; off < 256; off <<= 1) {
        int t = (threadIdx.x >= off) ? s[threadIdx.x - off] : 0;
        __syncthreads();
        s[threadIdx.x] += t;
        __syncthreads();
    }
    if (i < n) pre[i] = s[threadIdx.x] - v;
    if (threadIdx.x == 255) bsums[blockIdx.x] = s[255];
}

__global__ void scanB_kernel(int* __restrict__ bsums, int nb) {
    __shared__ int s[256];
    int v = (threadIdx.x < nb) ? bsums[threadIdx.x] : 0;
    s[threadIdx.x] = v;
    __syncthreads();
    for (int off = 1; off < 256; off <<= 1) {
        int t = (threadIdx.x >= off) ? s[threadIdx.x - off] : 0;
        __syncthreads();
        s[threadIdx.x] += t;
        __syncthreads();
    }
    if (threadIdx.x < nb) bsums[threadIdx.x] = s[threadIdx.x] - v;
}

__global__ void scanC_kernel(const int* __restrict__ pre, const int* __restrict__ bsums,
                             int* __restrict__ out, int n) {
    int i = blockIdx.x * 256 + threadIdx.x;
    if (i < n) out[i] = pre[i] + bsums[blockIdx.x];
}

__global__ void rowfin_kernel(const int* __restrict__ pre, const int* __restrict__ bsums,
                              int* __restrict__ row_start, int* __restrict__ cursor,
                              int N, int E) {
    int i = blockIdx.x * 256 + threadIdx.x;
    if (i < N) {
        int v = pre[i] + bsums[blockIdx.x];
        row_start[i] = v;
        cursor[i] = v;
    }
    if (i == 0) row_start[N] = E;
}

__global__ void scatter_kernel(const int* __restrict__ src, const int* __restrict__ dst,
                               const int* __restrict__ perm, const float* __restrict__ norm_out,
                               int* __restrict__ cursor, int* __restrict__ csr_src,
                               int* __restrict__ csr_perm, float* __restrict__ csr_norm, int E) {
    int e = blockIdx.x * 256 + threadIdx.x;
    if (e < E) {
        int d = dst[e];
        int s = src[e];
        int p = atomicAdd(cursor + d, 1);
        csr_src[p] = s;
        csr_perm[p] = perm[s];
        csr_norm[p] = norm_out[s];
    }
}

// ---------------- low-contention counting sort by deg_in ----------------
__global__ void histblk_kernel(const int* __restrict__ deg, int* __restrict__ hb,
                               int N, int nb) {
    __shared__ int h[256];
    h[threadIdx.x] = 0;
    __syncthreads();
    int i = blockIdx.x * 256 + threadIdx.x;
    if (i < N) atomicAdd(&h[min(deg[i], 255)], 1);
    __syncthreads();
    hb[threadIdx.x * nb + blockIdx.x] = h[threadIdx.x];
}

__global__ void place_kernel(const int* __restrict__ deg, const int* __restrict__ hbs,
                             int* __restrict__ order, int N, int nb) {
    __shared__ int cur[256];
    cur[threadIdx.x] = hbs[threadIdx.x * nb + blockIdx.x];
    __syncthreads();
    int i = blockIdx.x * 256 + threadIdx.x;
    if (i < N) {
        int b = min(deg[i], 255);
        int p = atomicAdd(&cur[b], 1);
        order[p] = i;
    }
}

// wsum[c] = row sums of Wm, bsum = sum(bm)
__global__ void wsum_kernel(const float* __restrict__ Wm, const float* __restrict__ bm,
                            float* __restrict__ wsum, float* __restrict__ bsum) {
    int c = threadIdx.x;
    if (c < H96) {
        float s = 0.f;
        for (int j = 0; j < H96; j++) s += Wm[c * H96 + j];
        wsum[c] = s;
    }
    if (c == 0) {
        float s = 0.f;
        for (int j = 0; j < H96; j++) s += bm[j];
        bsum[0] = s;
    }
}

// ---------------- bf16 hi/lo split helper ----------------
__device__ __forceinline__ void f2bf2(float v, unsigned short& h, unsigned short& l) {
    unsigned int b = __float_as_uint(v);
    unsigned short hh = (unsigned short)((b + 0x7FFFu + ((b >> 16) & 1u)) >> 16);
    float fh = __uint_as_float(((unsigned int)hh) << 16);
    float r = v - fh;
    unsigned int rb = __float_as_uint(r);
    unsigned short ll = (unsigned short)((rb + 0x7FFFu + ((rb >> 16) & 1u)) >> 16);
    h = hh; l = ll;
}

// W[K][96] fp32 -> Bt_hi/Bt_lo [96][KP] bf16 (transposed, zero-padded to KP)
__global__ void convB_kernel(const float* __restrict__ W, unsigned short* __restrict__ Bh,
                             unsigned short* __restrict__ Bl, int K, int KP) {
    int idx = blockIdx.x * 256 + threadIdx.x;
    if (idx < 96 * KP) {
        int n = idx / KP, k = idx - n * KP;
        float v = (k < K) ? W[(size_t)k * 96 + n] : 0.f;
        unsigned short h, l;
        f2bf2(v, h, l);
        Bh[idx] = h;
        Bl[idx] = l;
    }
}

// ---------------- bf16x3 MFMA GEMM: C[M,96] = A[M,K] @ B[K,96] (fp32-accurate) ----------------
// 256 threads = 4 waves; wave w computes rows [w*32, w*32+32) x 96 cols.
// A converted fp32->bf16 hi/lo during staging; B pre-transposed/split (Bt[96][KP]).
#define GBM 128
#define GBK 32
#define ASTR2 40   // ushorts per LDS row (32 + 8 pad); 80 B, 16B-aligned rows
__global__ __launch_bounds__(256) void gemm_mfma(const float* __restrict__ A,
                                                 const unsigned short* __restrict__ Bth,
                                                 const unsigned short* __restrict__ Btl,
                                                 float* __restrict__ C, int M, int K, int KP) {
    __shared__ unsigned short As_hi[GBM * ASTR2];
    __shared__ unsigned short As_lo[GBM * ASTR2];
    __shared__ unsigned short Bs_hi[96 * ASTR2];
    __shared__ unsigned short Bs_lo[96 * ASTR2];
    int tid = threadIdx.x;
    int row0 = blockIdx.x * GBM;
    int wid = tid >> 6, lane = tid & 63;
    int q = lane >> 4, mn = lane & 15;
    f32x4_t acc[2][6] = {};
    int nk = (K + GBK - 1) / GBK;

    for (int t = 0; t < nk; t++) {
        int k0 = t * GBK;
        // stage A: 128 rows x 32 k = 1024 float4, 4/thread; convert to hi/lo bf16
#pragma unroll
        for (int i = 0; i < 4; i++) {
            int idx = tid + i * 256;
            int r = idx >> 3, kq = idx & 7;
            int gr = row0 + r, gk = k0 + kq * 4;
            float4 v = make_float4(0.f, 0.f, 0.f, 0.f);
            if (gr < M) {
                if (gk + 4 <= K) {
                    v = *(const float4*)(A + (size_t)gr * K + gk);
                } else {
                    float tv[4] = {0.f, 0.f, 0.f, 0.f};
                    for (int c = 0; c < 4; c++)
                        if (gk + c < K) tv[c] = A[(size_t)gr * K + gk + c];
                    v = make_float4(tv[0], tv[1], tv[2], tv[3]);
                }
            }
            unsigned short h0, l0, h1, l1, h2, l2, h3, l3;
            f2bf2(v.x, h0, l0); f2bf2(v.y, h1, l1);
            f2bf2(v.z, h2, l2); f2bf2(v.w, h3, l3);
            uint2 hv = make_uint2((unsigned)h0 | ((unsigned)h1 << 16),
                                  (unsigned)h2 | ((unsigned)h3 << 16));
            uint2 lv = make_uint2((unsigned)l0 | ((unsigned)l1 << 16),
                                  (unsigned)l2 | ((unsigned)l3 << 16));
            *(uint2*)&As_hi[r * ASTR2 + kq * 4] = hv;
            *(uint2*)&As_lo[r * ASTR2 + kq * 4] = lv;
        }
        // stage B: 96 rows x 32 bf16 = 384 x 16B chunks (hi and lo)
#pragma unroll
        for (int i = 0; i < 2; i++) {
            int idx = tid + i * 256;
            if (idx < 384) {
                int n = idx >> 2, kc = idx & 3;
                uint4 hv = *(const uint4*)(Bth + (size_t)n * KP + k0 + kc * 8);
                uint4 lv = *(const uint4*)(Btl + (size_t)n * KP + k0 + kc * 8);
                *(uint4*)&Bs_hi[n * ASTR2 + kc * 8] = hv;
                *(uint4*)&Bs_lo[n * ASTR2 + kc * 8] = lv;
            }
        }
        __syncthreads();

        bf16x8_t ah[2], al[2], bh[6], bl[6];
#pragma unroll
        for (int rt = 0; rt < 2; rt++) {
            int r = wid * 32 + rt * 16 + mn;
            ah[rt] = *(const bf16x8_t*)&As_hi[r * ASTR2 + q * 8];
            al[rt] = *(const bf16x8_t*)&As_lo[r * ASTR2 + q * 8];
        }
#pragma unroll
        for (int ct = 0; ct < 6; ct++) {
            int n = ct * 16 + mn;
            bh[ct] = *(const bf16x8_t*)&Bs_hi[n * ASTR2 + q * 8];
            bl[ct] = *(const bf16x8_t*)&Bs_lo[n * ASTR2 + q * 8];
        }
#pragma unroll
        for (int rt = 0; rt < 2; rt++)
#pragma unroll
            for (int ct = 0; ct < 6; ct++) {
                acc[rt][ct] = __builtin_amdgcn_mfma_f32_16x16x32_bf16(ah[rt], bh[ct], acc[rt][ct], 0, 0, 0);
                acc[rt][ct] = __builtin_amdgcn_mfma_f32_16x16x32_bf16(ah[rt], bl[ct], acc[rt][ct], 0, 0, 0);
                acc[rt][ct] = __builtin_amdgcn_mfma_f32_16x16x32_bf16(al[rt], bh[ct], acc[rt][ct], 0, 0, 0);
            }
        __syncthreads();
    }

    // D layout: col = lane&15, row = (lane>>4)*4 + reg
#pragma unroll
    for (int rt = 0; rt < 2; rt++) {
#pragma unroll
        for (int reg = 0; reg < 4; reg++) {
            int gr = row0 + wid * 32 + rt * 16 + q * 4 + reg;
            if (gr < M) {
#pragma unroll
                for (int ct = 0; ct < 6; ct++)
                    C[(size_t)gr * H96 + ct * 16 + mn] = acc[rt][ct][reg];
            }
        }
    }
}

// ---------------- helpers ----------------
__device__ __forceinline__ void fma4(float4& a, float s, const float4& v) {
    a.x = fmaf(s, v.x, a.x);
    a.y = fmaf(s, v.y, a.y);
    a.z = fmaf(s, v.z, a.z);
    a.w = fmaf(s, v.w, a.w);
}

__device__ __forceinline__ float4 prelu4(float4 acc, float ni, float4 b, float4 a) {
    float4 h;
    h.x = fmaf(acc.x, ni, b.x); h.x = (h.x >= 0.f) ? h.x : a.x * h.x;
    h.y = fmaf(acc.y, ni, b.y); h.y = (h.y >= 0.f) ? h.y : a.y * h.y;
    h.z = fmaf(acc.z, ni, b.z); h.z = (h.z >= 0.f) ? h.z : a.z * h.z;
    h.w = fmaf(acc.w, ni, b.w); h.w = (h.w >= 0.f) ? h.w : a.w * h.w;
    return h;
}

// ---------------- layer-1 dual-view SpMM, float4, 8-edge unroll ----------------
__global__ __launch_bounds__(384) void spmm1_dual(
        const float4* __restrict__ y4, const int* __restrict__ row_start,
        const int* __restrict__ csr_src, const int* __restrict__ csr_perm,
        const float* __restrict__ csr_norm, const int* __restrict__ order,
        const float* __restrict__ norm_out, const float* __restrict__ norm_in,
        const float* __restrict__ b1, const float* __restrict__ a1,
        float4* __restrict__ h1, float4* __restrict__ h2, int N) {
    int g = blockIdx.x * 16 + threadIdx.y;
    if (g >= N) return;
    int d = order[g];
    int tx = threadIdx.x;
    int beg = row_start[d], end = row_start[d + 1];
    const float4* yt = y4 + tx;
    float4 acc1 = make_float4(0.f, 0.f, 0.f, 0.f);
    float4 acc2 = make_float4(0.f, 0.f, 0.f, 0.f);
    int j = beg;
    for (; j + 8 <= end; j += 8) {
        int s[8], p[8];
        float n[8];
#pragma unroll
        for (int q = 0; q < 8; q++) {
            s[q] = csr_src[j + q];
            p[q] = csr_perm[j + q];
            n[q] = csr_norm[j + q];
        }
        float4 u[8], w[8];
#pragma unroll
        for (int q = 0; q < 8; q++) u[q] = yt[(size_t)s[q] * 24];
#pragma unroll
        for (int q = 0; q < 8; q++) w[q] = yt[(size_t)p[q] * 24];
#pragma unroll
        for (int q = 0; q < 8; q++) { fma4(acc1, n[q], u[q]); fma4(acc2, n[q], w[q]); }
    }
    for (; j < end; j++) {
        int s = csr_src[j];
        int p = csr_perm[j];
        float n = csr_norm[j];
        fma4(acc1, n, yt[(size_t)s * 24]);
        fma4(acc2, n, yt[(size_t)p * 24]);
    }
    float ni = norm_in[d], no = norm_out[d];
    float4 bb = ((const float4*)b1)[tx];
    float4 aa = ((const float4*)a1)[tx];
    float4 r1 = prelu4(acc1, ni, bb, aa);
    float4 r2 = prelu4(acc2, ni, bb, aa);
    r1.x *= no; r1.y *= no; r1.z *= no; r1.w *= no;
    r2.x *= no; r2.y *= no; r2.z *= no; r2.w *= no;
    h1[(size_t)d * 24 + tx] = r1;
    h2[(size_t)d * 24 + tx] = r2;
}

// ---------------- layer-2 dual-view SpMM + fused final dot, 8-edge unroll ----------------
__global__ __launch_bounds__(384) void spmm2_dual(
        const float4* __restrict__ t4,
        const int* __restrict__ row_start, const int* __restrict__ csr_src,
        const int* __restrict__ order, const float* __restrict__ norm_in,
        const float* __restrict__ b2, const float* __restrict__ a2,
        const float* __restrict__ wsum, const float* __restrict__ bsum,
        float* __restrict__ outp, int N) {
    int g = blockIdx.x * 16 + threadIdx.y;
    int tx = threadIdx.x;
    int ty = threadIdx.y;
    bool valid = (g < N);
    int d = valid ? order[g] : 0;
    int beg = 0, end = 0;
    if (valid) { beg = row_start[d]; end = row_start[d + 1]; }
    const float4* t1 = t4 + tx;
    const float4* t2 = t4 + (size_t)N * 24 + tx;
    float4 acc1 = make_float4(0.f, 0.f, 0.f, 0.f);
    float4 acc2 = make_float4(0.f, 0.f, 0.f, 0.f);
    int j = beg;
    for (; j + 8 <= end; j += 8) {
        int s[8];
#pragma unroll
        for (int q = 0; q < 8; q++) s[q] = csr_src[j + q];
        float4 u[8], w[8];
#pragma unroll
        for (int q = 0; q < 8; q++) u[q] = t1[(size_t)s[q] * 24];
#pragma unroll
        for (int q = 0; q < 8; q++) w[q] = t2[(size_t)s[q] * 24];
#pragma unroll
        for (int q = 0; q < 8; q++) { fma4(acc1, 1.f, u[q]); fma4(acc2, 1.f, w[q]); }
    }
    for (; j < end; j++) {
        int s = csr_src[j];
        fma4(acc1, 1.f, t1[(size_t)s * 24]);
        fma4(acc2, 1.f, t2[(size_t)s * 24]);
    }
    float ni = valid ? norm_in[d] : 0.f;
    float4 bb = ((const float4*)b2)[tx];
    float4 aa = ((const float4*)a2)[tx];
    float4 wv = ((const float4*)wsum)[tx];
    float4 r1 = prelu4(acc1, ni, bb, aa);
    float4 r2 = prelu4(acc2, ni, bb, aa);
    float p1 = r1.x * wv.x + r1.y * wv.y + r1.z * wv.z + r1.w * wv.w;
    float p2 = r2.x * wv.x + r2.y * wv.y + r2.z * wv.z + r2.w * wv.w;
    __shared__ float red1[16][24];
    __shared__ float red2[16][24];
    red1[ty][tx] = p1;
    red2[ty][tx] = p2;
    __syncthreads();
    if (tx == 0 && valid) {
        float s1 = 0.f, s2 = 0.f;
#pragma unroll
        for (int k = 0; k < 24; k++) { s1 += red1[ty][k]; s2 += red2[ty][k]; }
        outp[d] = s1 + bsum[0];
        outp[N + d] = s2 + bsum[0];
    }
}

extern "C" void kernel_launch(void* const* d_in, const int* in_sizes, int n_in,
                              void* d_out, int out_size, void* d_ws, size_t ws_size,
                              hipStream_t stream) {
    const float* x    = (const float*)d_in[0];
    const int*   src  = (const int*)d_in[1];
    const int*   dst  = (const int*)d_in[2];
    const int*   perm = (const int*)d_in[3];
    const float* W1   = (const float*)d_in[4];
    const float* b1   = (const float*)d_in[5];
    const float* a1   = (const float*)d_in[6];
    const float* W2   = (const float*)d_in[7];
    const float* b2   = (const float*)d_in[8];
    const float* a2   = (const float*)d_in[9];
    const float* Wm   = (const float*)d_in[10];
    const float* bm   = (const float*)d_in[11];
    float* out = (float*)d_out;

    int E = in_sizes[1];
    int N = in_sizes[3];
    int F = in_sizes[0] / N;               // 500
    int KP1 = ((F + GBK - 1) / GBK) * GBK; // 512 (padded K for transposed W1)

    size_t NP = ((size_t)N + 256) & ~(size_t)255;
    size_t EP = ((size_t)E + 255) & ~(size_t)255;
    int nb = (N + 255) / 256;
    size_t HB = ((size_t)256 * nb + 255) & ~(size_t)255;

    int* deg_out   = (int*)d_ws;          // NP
    int* deg_in    = deg_out + NP;        // NP
    int* pre       = deg_in + NP;         // NP
    int* row_start = pre + NP;            // NP
    int* cursor    = row_start + NP;      // NP
    int* order     = cursor + NP;         // NP
    int* bsums     = order + NP;          // 256
    int* hb        = bsums + 256;         // HB
    int* hbs       = hb + HB;             // HB
    int* hpre      = hbs + HB;            // HB
    int* csr_src   = hpre + HB;           // EP
    int* csr_perm  = csr_src + EP;        // EP
    float* csr_norm = (float*)(csr_perm + EP); // EP
    float* norm_out = csr_norm + EP;           // NP
    float* norm_in  = norm_out + NP;           // NP
    float* wsum     = norm_in + NP;            // 128
    float* bsum     = wsum + 128;              // 128
    unsigned short* w1th = (unsigned short*)(bsum + 128); // 96*KP1 (49152) pad to 49664
    unsigned short* w1tl = w1th + 49664;
    unsigned short* w2th = w1tl + 49664;                  // 96*96 (9216) pad to 9728
    unsigned short* w2tl = w2th + 9728;
    float* tbuf = (float*)(w2tl + 9728);           // 2N*96 (first N*96 doubles as y)
    float* h1s  = tbuf + (size_t)2 * N * H96;      // 2N*96

    hipMemsetAsync(deg_out, 0, 2 * NP * sizeof(int), stream);
    deg_kernel<<<(E + 255) / 256, 256, 0, stream>>>(src, dst, deg_out, deg_in, E);
    norm_kernel<<<(N + 255) / 256, 256, 0, stream>>>(deg_out, deg_in, norm_out, norm_in, N);

    scanA_kernel<<<nb, 256, 0, stream>>>(deg_in, pre, bsums, N);
    scanB_kernel<<<1, 256, 0, stream>>>(bsums, nb);
    rowfin_kernel<<<nb, 256, 0, stream>>>(pre, bsums, row_start, cursor, N, E);
    scatter_kernel<<<(E + 255) / 256, 256, 0, stream>>>(src, dst, perm, norm_out, cursor,
                                                        csr_src, csr_perm, csr_norm, E);

    histblk_kernel<<<nb, 256, 0, stream>>>(deg_in, hb, N, nb);
    int n2 = 256 * nb;
    int nb2 = (n2 + 255) / 256;
    scanA_kernel<<<nb2, 256, 0, stream>>>(hb, hpre, bsums, n2);
    scanB_kernel<<<1, 256, 0, stream>>>(bsums, nb2);
    scanC_kernel<<<nb2, 256, 0, stream>>>(hpre, bsums, hbs, n2);
    place_kernel<<<nb, 256, 0, stream>>>(deg_in, hbs, order, N, nb);

    wsum_kernel<<<1, 128, 0, stream>>>(Wm, bm, wsum, bsum);

    // pre-transpose + bf16-split weights
    convB_kernel<<<(96 * KP1 + 255) / 256, 256, 0, stream>>>(W1, w1th, w1tl, F, KP1);
    convB_kernel<<<(96 * 96 + 255) / 256, 256, 0, stream>>>(W2, w2th, w2tl, H96, H96);

    float* y = tbuf;  // reuse: y dead before tbuf is written
    // y = x @ W1 via bf16x3 MFMA
    gemm_mfma<<<(N + GBM - 1) / GBM, 256, 0, stream>>>(x, w1th, w1tl, y, N, F, KP1);

    int nsb = (N + 15) / 16;
    spmm1_dual<<<nsb, dim3(24, 16), 0, stream>>>(
        (const float4*)y, row_start, csr_src, csr_perm, csr_norm, order, norm_out, norm_in,
        b1, a1, (float4*)h1s, (float4*)(h1s + (size_t)N * H96), N);

    // tbuf[2N,96] = h1s @ W2 via bf16x3 MFMA
    gemm_mfma<<<(2 * N + GBM - 1) / GBM, 256, 0, stream>>>(h1s, w2th, w2tl, tbuf, 2 * N, H96, H96);

    spmm2_dual<<<nsb, dim3(24, 16), 0, stream>>>(
        (const float4*)tbuf, row_start, csr_src, order, norm_in, b2, a2,
        wsum, bsum, out, N);
}